// Round 2
// baseline (594.145 us; speedup 1.0000x reference)
//
#include <hip/hip_runtime.h>
#include <hip/hip_bf16.h>
#include <cstdint>

typedef __attribute__((ext_vector_type(4))) float f32x4;
typedef __attribute__((ext_vector_type(4))) int i32x4;

#define IN_F 4096
#define OUT_F 4096
#define N_TOK 8192
#define NUM_FREQ 16

// ---------- helpers ----------

__device__ inline float fast_tanh(float x) {
    float ax = fabsf(x);
    float e = __expf(2.0f * ax);
    float t = 1.0f - 2.0f / (e + 1.0f);
    return copysignf(t, x);
}

__device__ inline void load_lds16(const void* g, void* l) {
    __builtin_amdgcn_global_load_lds(
        (const __attribute__((address_space(1))) void*)(uintptr_t)g,
        (__attribute__((address_space(3))) void*)(uint32_t)(uintptr_t)l,
        16, 0, 0);
}

__device__ inline int q8(float v, float s) {
    int q = (int)rintf(v * s);
    return min(127, max(-127, q));
}

__device__ inline unsigned int pack4(int q0, int q1, int q2, int q3) {
    return (q0 & 255) | ((q1 & 255) << 8) | ((q2 & 255) << 16) |
           ((q3 & 255) << 24);
}

// ---------- kernel 0: column-cosine table ----------
// Ccos[i][k] = cos(step*i*cf[k] + cp[k]) depends only on (i,k) — it was
// being recomputed by all 4096 W-row blocks (2.7e8 cos). Compute once:
// 65k cos, 256 KB table, L2-resident for the prep pass.
__global__ __launch_bounds__(256)
void tab(const float* __restrict__ cf, const float* __restrict__ cp,
         float* __restrict__ ct) {
    const int i = blockIdx.x * 256 + threadIdx.x;
    const float step = 6.28318530717958647692f / 4095.0f;
    const float ci = step * (float)i;
    float v[NUM_FREQ];
#pragma unroll
    for (int k = 0; k < NUM_FREQ; ++k) v[k] = __cosf(ci * cf[k] + cp[k]);
    f32x4* out = (f32x4*)(ct + (size_t)i * NUM_FREQ);
#pragma unroll
    for (int q = 0; q < 4; ++q) {
        f32x4 o4;
        o4[0] = v[q * 4 + 0];
        o4[1] = v[q * 4 + 1];
        o4[2] = v[q * 4 + 2];
        o4[3] = v[q * 4 + 3];
        out[q] = o4;
    }
}

// ---------- kernel 1: fused W synthesis->i8 + x quantize->i8 ----------
// blocks [0, OUT_F)               : synth W row o (table FMA), quantize
// blocks [OUT_F, OUT_F + N_TOK)   : quantize x row t, per-row absmax
__global__ __launch_bounds__(256)
void prep(const float* __restrict__ x, signed char* __restrict__ xq,
          float* __restrict__ sx, const float* __restrict__ amp,
          const float* __restrict__ rf, const float* __restrict__ cf,
          const float* __restrict__ rp, const float* __restrict__ cp,
          const float* __restrict__ lA, const float* __restrict__ lB,
          const float* __restrict__ alpha, const float* __restrict__ beta,
          signed char* __restrict__ wq, float* __restrict__ sw,
          const float* __restrict__ ct) {
    const int tid = threadIdx.x;
    const int wave = tid >> 6;
    const int lane = tid & 63;
    __shared__ float s_s[NUM_FREQ];
    __shared__ float red[4];

    if (blockIdx.x < OUT_F) {
        // ---- W synthesis + quantize ----
        const int o = blockIdx.x;
        const float step = 6.28318530717958647692f / 4095.0f;
        if (tid < NUM_FREQ) {
            float r = step * (float)o;
            s_s[tid] = amp[tid] * __sinf(r * rf[tid] + rp[tid]);
        }
        __syncthreads();
        float sk[NUM_FREQ];
#pragma unroll
        for (int k = 0; k < NUM_FREQ; ++k) sk[k] = s_s[k];

        const float sa = 1.0f / (1.0f + __expf(-alpha[0]));
        const float sb = 1.0f / (1.0f + __expf(-beta[0]));
        const float stdv = 0.015625f;  // sqrt(2/8192) = 1/64 exactly
        const float a0 = lA[o * 2 + 0];
        const float a1 = lA[o * 2 + 1];

        float w[16];
        const int ibase = tid * 16;
        const f32x4* lB4 = (const f32x4*)lB;
        const f32x4* ct4 = (const f32x4*)ct;  // f32x4 index = i*4 + q
#pragma unroll
        for (int g = 0; g < 4; ++g) {
            f32x4 b0 = lB4[tid * 4 + g];
            f32x4 b1 = lB4[1024 + tid * 4 + g];
#pragma unroll
            for (int e = 0; e < 4; ++e) {
                int j = g * 4 + e;
                float wf = 0.0f;
#pragma unroll
                for (int q = 0; q < 4; ++q) {
                    f32x4 cv = ct4[(size_t)(ibase + j) * 4 + q];
                    wf += sk[q * 4 + 0] * cv[0];
                    wf += sk[q * 4 + 1] * cv[1];
                    wf += sk[q * 4 + 2] * cv[2];
                    wf += sk[q * 4 + 3] * cv[3];
                }
                float wl = a0 * b0[e] + a1 * b1[e];
                w[j] = sa * stdv * fast_tanh(wf) + sb * stdv * fast_tanh(wl);
            }
        }
        // block absmax reduction
        float m = 0.0f;
#pragma unroll
        for (int j = 0; j < 16; ++j) m = fmaxf(m, fabsf(w[j]));
#pragma unroll
        for (int off = 32; off > 0; off >>= 1)
            m = fmaxf(m, __shfl_xor(m, off));
        if (lane == 0) red[wave] = m;
        __syncthreads();
        m = fmaxf(fmaxf(red[0], red[1]), fmaxf(red[2], red[3]));
        m = fmaxf(m, 1e-20f);
        const float s = 127.0f / m;
        uint4 out;
        unsigned int* op = (unsigned int*)&out;
#pragma unroll
        for (int g = 0; g < 4; ++g)
            op[g] = pack4(q8(w[g * 4], s), q8(w[g * 4 + 1], s),
                          q8(w[g * 4 + 2], s), q8(w[g * 4 + 3], s));
        *(uint4*)(wq + (size_t)o * IN_F + ibase) = out;
        if (tid == 0) sw[o] = m / 127.0f;
    } else {
        // ---- x quantize ----
        const int t = blockIdx.x - OUT_F;
        const f32x4* xr = (const f32x4*)(x + (size_t)t * IN_F);
        f32x4 v[4];
#pragma unroll
        for (int j = 0; j < 4; ++j) v[j] = xr[tid + 256 * j];
        float m = 0.0f;
#pragma unroll
        for (int j = 0; j < 4; ++j)
#pragma unroll
            for (int e = 0; e < 4; ++e) m = fmaxf(m, fabsf(v[j][e]));
#pragma unroll
        for (int off = 32; off > 0; off >>= 1)
            m = fmaxf(m, __shfl_xor(m, off));
        if (lane == 0) red[wave] = m;
        __syncthreads();
        m = fmaxf(fmaxf(red[0], red[1]), fmaxf(red[2], red[3]));
        m = fmaxf(m, 1e-20f);
        const float s = 127.0f / m;
        unsigned int* orow = (unsigned int*)(xq + (size_t)t * IN_F);
#pragma unroll
        for (int j = 0; j < 4; ++j)
            orow[tid + 256 * j] =
                pack4(q8(v[j][0], s), q8(v[j][1], s), q8(v[j][2], s),
                      q8(v[j][3], s));
        if (tid == 0) sx[t] = m / 127.0f;
    }
}

// ---------- kernel 2: i8 MFMA GEMM, C = (sx.sw^T) * (Aq @ Bq^T) + bias ----
// UNCHANGED this round (clean attribution for the prep change).
// Known state: SQ_LDS_BANK_CONFLICT == 0 (XOR swizzle verified), MfmaUtil
// ~37% — latency/barrier-bound at the classic 2-barrier-per-K-step ceiling.
// Next structural lever (future round): 8-phase counted-vmcnt schedule.
#define BM 256
#define BN 128
#define BKB 128
#define SUBK 64

__global__ __launch_bounds__(256, 2)
void gemm_i8(const signed char* __restrict__ A, const signed char* __restrict__ B,
             const float* __restrict__ sx, const float* __restrict__ sw,
             const float* __restrict__ bias, float* __restrict__ C,
             int M, int N, int K) {
    __shared__ signed char sA[2][BM * SUBK];  // 2 x 16 KB
    __shared__ signed char sB[2][BN * SUBK];  // 2 x 8 KB

    const int tid = threadIdx.x;
    const int wave = tid >> 6;
    const int lane = tid & 63;

    const int bm = blockIdx.y * BM;
    const int bn = blockIdx.x * BN;

    // staging: one call = 16 rows x 64B (1KB, linear in LDS).
    // lane l -> row = l>>2 (within chunk), slot s = l&3.
    // source column unit = s ^ ((row>>1)&3) = s ^ ((l>>3)&3)  [swizzle]
    const int srow = lane >> 2;
    const int scol = (((lane & 3) ^ ((lane >> 3) & 3)) << 4);

    const signed char* gA = A + (size_t)(bm + wave * 16 + srow) * K + scol;
    const signed char* gB = B + (size_t)(bn + wave * 16 + srow) * K + scol;

    // reads: row = (wtile + i*16 + lm), 16B unit = quad ^ ((row>>1)&3);
    // (row>>1)&3 == (lm>>1)&3 because all other row terms are mult of 16.
    const int lm = lane & 15;
    const int quad = lane >> 4;
    const int kq = ((quad ^ ((lm >> 1) & 3)) << 4);

    const int wm = (wave & 1) * 128;  // wave M offset in tile
    const int wn = (wave >> 1) * 64;  // wave N offset in tile
    const int aoff = (wm + lm) * SUBK + kq;
    const int boff = (wn + lm) * SUBK + kq;

    i32x4 acc[8][4] = {};

    for (int k0 = 0; k0 < K; k0 += BKB) {
#pragma unroll
        for (int h = 0; h < 2; ++h) {
            const int kk = k0 + h * SUBK;
#pragma unroll
            for (int c = 0; c < 4; ++c)
                load_lds16(gA + (size_t)c * 64 * K + kk,
                           &sA[h][(wave * 16 + c * 64) * SUBK]);
#pragma unroll
            for (int c = 0; c < 2; ++c)
                load_lds16(gB + (size_t)c * 64 * K + kk,
                           &sB[h][(wave * 16 + c * 64) * SUBK]);
        }
        __syncthreads();

#pragma unroll
        for (int h = 0; h < 2; ++h) {
            i32x4 af[8], bv[4];
#pragma unroll
            for (int i = 0; i < 8; ++i)
                af[i] = *(const i32x4*)&sA[h][aoff + i * 16 * SUBK];
#pragma unroll
            for (int i = 0; i < 4; ++i)
                bv[i] = *(const i32x4*)&sB[h][boff + i * 16 * SUBK];

#pragma unroll
            for (int im = 0; im < 8; ++im)
#pragma unroll
                for (int in = 0; in < 4; ++in)
                    acc[im][in] = __builtin_amdgcn_mfma_i32_16x16x64_i8(
                        af[im], bv[in], acc[im][in], 0, 0, 0);
        }

        __syncthreads();
    }

    // epilogue: D layout col = lane&15, row = quad*4 + r
    float sxv[8][4];
#pragma unroll
    for (int im = 0; im < 8; ++im)
#pragma unroll
        for (int r = 0; r < 4; ++r)
            sxv[im][r] = sx[bm + wm + im * 16 + quad * 4 + r];

#pragma unroll
    for (int in = 0; in < 4; ++in) {
        const int cn = bn + wn + in * 16 + lm;
        const float bv_ = bias[cn];
        const float scw = sw[cn];
#pragma unroll
        for (int im = 0; im < 8; ++im) {
            const int rm = bm + wm + im * 16 + quad * 4;
#pragma unroll
            for (int r = 0; r < 4; ++r)
                C[(size_t)(rm + r) * N + cn] =
                    (float)acc[im][in][r] * (sxv[im][r] * scw) + bv_;
        }
    }
}

// ---------- launch ----------
extern "C" void kernel_launch(void* const* d_in, const int* in_sizes, int n_in,
                              void* d_out, int out_size, void* d_ws,
                              size_t ws_size, hipStream_t stream) {
    const float* x = (const float*)d_in[0];
    const float* amp = (const float*)d_in[1];
    const float* rf = (const float*)d_in[2];
    const float* cf = (const float*)d_in[3];
    const float* rp = (const float*)d_in[4];
    const float* cp = (const float*)d_in[5];
    const float* lA = (const float*)d_in[6];
    const float* lB = (const float*)d_in[7];
    const float* alpha = (const float*)d_in[8];
    const float* beta = (const float*)d_in[9];
    const float* bias = (const float*)d_in[10];
    float* out = (float*)d_out;

    signed char* wq = (signed char*)d_ws;                       // 16 MiB
    signed char* xq = wq + (size_t)OUT_F * IN_F;                // 32 MiB
    float* sw = (float*)(xq + (size_t)N_TOK * IN_F);            // 16 KiB
    float* sx = sw + OUT_F;                                     // 32 KiB
    float* ct = sx + N_TOK;                                     // 256 KiB

    tab<<<IN_F / 256, 256, 0, stream>>>(cf, cp, ct);
    prep<<<OUT_F + N_TOK, 256, 0, stream>>>(x, xq, sx, amp, rf, cf, rp, cp,
                                            lA, lB, alpha, beta, wq, sw, ct);
    gemm_i8<<<dim3(OUT_F / BN, N_TOK / BM), 256, 0, stream>>>(
        xq, wq, sx, sw, bias, out, N_TOK, OUT_F, IN_F);
}

// Round 3
// 430.017 us; speedup vs baseline: 1.3817x; 1.3817x over previous
//
#include <hip/hip_runtime.h>
#include <hip/hip_bf16.h>
#include <cstdint>

typedef __attribute__((ext_vector_type(4))) float f32x4;
typedef __attribute__((ext_vector_type(4))) int i32x4;

#define IN_F 4096
#define OUT_F 4096
#define N_TOK 8192
#define NUM_FREQ 16
#define RROWS 4  // W rows per block (amortizes per-column cosines 4x)

// ---------- helpers ----------

__device__ inline float fast_tanh(float x) {
    float ax = fabsf(x);
    float e = __expf(2.0f * ax);
    float t = 1.0f - 2.0f / (e + 1.0f);
    return copysignf(t, x);
}

__device__ inline void load_lds16(const void* g, void* l) {
    __builtin_amdgcn_global_load_lds(
        (const __attribute__((address_space(1))) void*)(uintptr_t)g,
        (__attribute__((address_space(3))) void*)(uint32_t)(uintptr_t)l,
        16, 0, 0);
}

__device__ inline int q8(float v, float s) {
    int q = (int)rintf(v * s);
    return min(127, max(-127, q));
}

__device__ inline unsigned int pack4(int q0, int q1, int q2, int q3) {
    return (q0 & 255) | ((q1 & 255) << 8) | ((q2 & 255) << 16) |
           ((q3 & 255) << 24);
}

// ---------- kernel 1: fused W synthesis->i8 + x quantize->i8 ----------
// blocks [0, OUT_F/RROWS)     : synth W rows [4b, 4b+4), quantize per row
// blocks [OUT_F/RROWS, +N_TOK): quantize x row t
//
// Round-3 W-path redesign (r2 post-mortem: [i][16] table reads gave each
// lane a private 64B row -> 1KB lane stride -> 64 cache lines PER wave-op;
// prep was TA/latency-bound with every pipe <16% busy, and the scatter
// starved the co-resident x-quant blocks down to 446 GB/s):
//  - frequencies quad-split across lanes: lane quad q owns freqs 4q..4q+3,
//    computes its 4 cosines IN-REGISTER (no table, no tab dispatch),
//    4 FMAs, then __shfl_xor(1,2) quad-reduce (DPP, VALU-rate).
//  - RROWS=4 rows/block: each block computes the column cosines once for
//    4 rows -> total trig 2.7e8 -> 6.7e7 (~6us VALU issue).
//  - all global loads (lB) and i8 stores are contiguous permuted 64B
//    segments per wave-op (fully coalesced).
__global__ __launch_bounds__(256)
void prep(const float* __restrict__ x, signed char* __restrict__ xq,
          float* __restrict__ sx, const float* __restrict__ amp,
          const float* __restrict__ rf, const float* __restrict__ cf,
          const float* __restrict__ rp, const float* __restrict__ cp,
          const float* __restrict__ lA, const float* __restrict__ lB,
          const float* __restrict__ alpha, const float* __restrict__ beta,
          signed char* __restrict__ wq, float* __restrict__ sw) {
    const int tid = threadIdx.x;
    const int wave = tid >> 6;
    const int lane = tid & 63;
    __shared__ float s_s[RROWS][NUM_FREQ];
    __shared__ float red[RROWS][4];

    if (blockIdx.x < OUT_F / RROWS) {
        // ---- W synthesis + quantize, rows o0..o0+3 ----
        const int o0 = blockIdx.x * RROWS;
        const float step = 6.28318530717958647692f / 4095.0f;
        if (tid < RROWS * NUM_FREQ) {
            const int r = tid >> 4;
            const int k = tid & 15;
            s_s[r][k] =
                amp[k] * __sinf(step * (float)(o0 + r) * rf[k] + rp[k]);
        }
        __syncthreads();

        const int g = lane >> 2;   // element sub-index within 16-group
        const int q = lane & 3;    // freq quad owned by this lane

        float cfr[4], cpr[4];
#pragma unroll
        for (int e = 0; e < 4; ++e) {
            cfr[e] = cf[q * 4 + e];
            cpr[e] = cp[q * 4 + e];
        }
        float skr[RROWS][4];
#pragma unroll
        for (int r = 0; r < RROWS; ++r)
#pragma unroll
            for (int e = 0; e < 4; ++e) skr[r][e] = s_s[r][q * 4 + e];

        const float sa = 1.0f / (1.0f + __expf(-alpha[0]));
        const float sb = 1.0f / (1.0f + __expf(-beta[0]));
        const float stdv = 0.015625f;  // sqrt(2/8192) = 1/64 exactly
        float a0r[RROWS], a1r[RROWS];
#pragma unroll
        for (int r = 0; r < RROWS; ++r) {
            a0r[r] = lA[(o0 + r) * 2 + 0];
            a1r[r] = lA[(o0 + r) * 2 + 1];
        }

        const int ibw = wave * 1024;  // this wave's column range [ibw,+1024)
        float w[RROWS][16];

        // Fourier part. Lane's owned element for slot j is
        // i_own(j) = ibw + (j*4+q)*16 + g; during slot (j,sq) the 4-lane
        // group jointly computes element ibw + (j*4+sq)*16 + g.
#pragma unroll
        for (int j = 0; j < 16; ++j) {
#pragma unroll
            for (int sq = 0; sq < 4; ++sq) {
                const int i = ibw + (j * 4 + sq) * 16 + g;
                const float ci = step * (float)i;
                float cv[4];
#pragma unroll
                for (int e = 0; e < 4; ++e)
                    cv[e] = __cosf(ci * cfr[e] + cpr[e]);
#pragma unroll
                for (int r = 0; r < RROWS; ++r) {
                    float p = skr[r][0] * cv[0] + skr[r][1] * cv[1] +
                              skr[r][2] * cv[2] + skr[r][3] * cv[3];
                    p += __shfl_xor(p, 1);
                    p += __shfl_xor(p, 2);
                    if (q == sq) w[r][j] = p;
                }
            }
        }

        // lora + tanh combine (b0/b1 loads: 64B-segment coalesced)
#pragma unroll
        for (int j = 0; j < 16; ++j) {
            const int i = ibw + (j * 4 + q) * 16 + g;
            const float b0 = lB[i];
            const float b1 = lB[IN_F + i];
#pragma unroll
            for (int r = 0; r < RROWS; ++r) {
                const float wl = a0r[r] * b0 + a1r[r] * b1;
                w[r][j] = sa * stdv * fast_tanh(w[r][j]) +
                          sb * stdv * fast_tanh(wl);
            }
        }

        // per-row absmax over the block
        float m[RROWS];
#pragma unroll
        for (int r = 0; r < RROWS; ++r) {
            float mm = 0.0f;
#pragma unroll
            for (int j = 0; j < 16; ++j) mm = fmaxf(mm, fabsf(w[r][j]));
#pragma unroll
            for (int off = 32; off > 0; off >>= 1)
                mm = fmaxf(mm, __shfl_xor(mm, off));
            m[r] = mm;
        }
        if (lane == 0) {
#pragma unroll
            for (int r = 0; r < RROWS; ++r) red[r][wave] = m[r];
        }
        __syncthreads();
#pragma unroll
        for (int r = 0; r < RROWS; ++r) {
            float mm = fmaxf(fmaxf(red[r][0], red[r][1]),
                             fmaxf(red[r][2], red[r][3]));
            m[r] = fmaxf(mm, 1e-20f);
        }

        // quantize + store (per (r,j): wave writes one permuted 64B segment)
#pragma unroll
        for (int r = 0; r < RROWS; ++r) {
            const float s = 127.0f / m[r];
            signed char* wrow = wq + (size_t)(o0 + r) * IN_F;
#pragma unroll
            for (int j = 0; j < 16; ++j) {
                const int i = ibw + (j * 4 + q) * 16 + g;
                wrow[i] = (signed char)q8(w[r][j], s);
            }
        }
        if (tid == 0) {
#pragma unroll
            for (int r = 0; r < RROWS; ++r) sw[o0 + r] = m[r] / 127.0f;
        }
    } else {
        // ---- x quantize ----
        const int t = blockIdx.x - OUT_F / RROWS;
        const f32x4* xr = (const f32x4*)(x + (size_t)t * IN_F);
        f32x4 v[4];
#pragma unroll
        for (int j = 0; j < 4; ++j) v[j] = xr[tid + 256 * j];
        float m = 0.0f;
#pragma unroll
        for (int j = 0; j < 4; ++j)
#pragma unroll
            for (int e = 0; e < 4; ++e) m = fmaxf(m, fabsf(v[j][e]));
#pragma unroll
        for (int off = 32; off > 0; off >>= 1)
            m = fmaxf(m, __shfl_xor(m, off));
        if (lane == 0) red[0][wave] = m;
        __syncthreads();
        m = fmaxf(fmaxf(red[0][0], red[0][1]), fmaxf(red[0][2], red[0][3]));
        m = fmaxf(m, 1e-20f);
        const float s = 127.0f / m;
        unsigned int* orow = (unsigned int*)(xq + (size_t)t * IN_F);
#pragma unroll
        for (int j = 0; j < 4; ++j)
            orow[tid + 256 * j] =
                pack4(q8(v[j][0], s), q8(v[j][1], s), q8(v[j][2], s),
                      q8(v[j][3], s));
        if (tid == 0) sx[t] = m / 127.0f;
    }
}

// ---------- kernel 2: i8 MFMA GEMM, C = (sx.sw^T) * (Aq @ Bq^T) + bias ----
// UNCHANGED this round (clean attribution for the prep change).
// Known state: SQ_LDS_BANK_CONFLICT == 0 (XOR swizzle verified), MfmaUtil
// ~37% — latency/barrier-bound at the classic 2-barrier-per-K-step ceiling.
// Next structural lever (future round): 8-phase counted-vmcnt schedule.
#define BM 256
#define BN 128
#define BKB 128
#define SUBK 64

__global__ __launch_bounds__(256, 2)
void gemm_i8(const signed char* __restrict__ A, const signed char* __restrict__ B,
             const float* __restrict__ sx, const float* __restrict__ sw,
             const float* __restrict__ bias, float* __restrict__ C,
             int M, int N, int K) {
    __shared__ signed char sA[2][BM * SUBK];  // 2 x 16 KB
    __shared__ signed char sB[2][BN * SUBK];  // 2 x 8 KB

    const int tid = threadIdx.x;
    const int wave = tid >> 6;
    const int lane = tid & 63;

    const int bm = blockIdx.y * BM;
    const int bn = blockIdx.x * BN;

    // staging: one call = 16 rows x 64B (1KB, linear in LDS).
    // lane l -> row = l>>2 (within chunk), slot s = l&3.
    // source column unit = s ^ ((row>>1)&3) = s ^ ((l>>3)&3)  [swizzle]
    const int srow = lane >> 2;
    const int scol = (((lane & 3) ^ ((lane >> 3) & 3)) << 4);

    const signed char* gA = A + (size_t)(bm + wave * 16 + srow) * K + scol;
    const signed char* gB = B + (size_t)(bn + wave * 16 + srow) * K + scol;

    // reads: row = (wtile + i*16 + lm), 16B unit = quad ^ ((row>>1)&3);
    // (row>>1)&3 == (lm>>1)&3 because all other row terms are mult of 16.
    const int lm = lane & 15;
    const int quad = lane >> 4;
    const int kq = ((quad ^ ((lm >> 1) & 3)) << 4);

    const int wm = (wave & 1) * 128;  // wave M offset in tile
    const int wn = (wave >> 1) * 64;  // wave N offset in tile
    const int aoff = (wm + lm) * SUBK + kq;
    const int boff = (wn + lm) * SUBK + kq;

    i32x4 acc[8][4] = {};

    for (int k0 = 0; k0 < K; k0 += BKB) {
#pragma unroll
        for (int h = 0; h < 2; ++h) {
            const int kk = k0 + h * SUBK;
#pragma unroll
            for (int c = 0; c < 4; ++c)
                load_lds16(gA + (size_t)c * 64 * K + kk,
                           &sA[h][(wave * 16 + c * 64) * SUBK]);
#pragma unroll
            for (int c = 0; c < 2; ++c)
                load_lds16(gB + (size_t)c * 64 * K + kk,
                           &sB[h][(wave * 16 + c * 64) * SUBK]);
        }
        __syncthreads();

#pragma unroll
        for (int h = 0; h < 2; ++h) {
            i32x4 af[8], bv[4];
#pragma unroll
            for (int i = 0; i < 8; ++i)
                af[i] = *(const i32x4*)&sA[h][aoff + i * 16 * SUBK];
#pragma unroll
            for (int i = 0; i < 4; ++i)
                bv[i] = *(const i32x4*)&sB[h][boff + i * 16 * SUBK];

#pragma unroll
            for (int im = 0; im < 8; ++im)
#pragma unroll
                for (int in = 0; in < 4; ++in)
                    acc[im][in] = __builtin_amdgcn_mfma_i32_16x16x64_i8(
                        af[im], bv[in], acc[im][in], 0, 0, 0);
        }

        __syncthreads();
    }

    // epilogue: D layout col = lane&15, row = quad*4 + r
    float sxv[8][4];
#pragma unroll
    for (int im = 0; im < 8; ++im)
#pragma unroll
        for (int r = 0; r < 4; ++r)
            sxv[im][r] = sx[bm + wm + im * 16 + quad * 4 + r];

#pragma unroll
    for (int in = 0; in < 4; ++in) {
        const int cn = bn + wn + in * 16 + lm;
        const float bv_ = bias[cn];
        const float scw = sw[cn];
#pragma unroll
        for (int im = 0; im < 8; ++im) {
            const int rm = bm + wm + im * 16 + quad * 4;
#pragma unroll
            for (int r = 0; r < 4; ++r)
                C[(size_t)(rm + r) * N + cn] =
                    (float)acc[im][in][r] * (sxv[im][r] * scw) + bv_;
        }
    }
}

// ---------- launch ----------
extern "C" void kernel_launch(void* const* d_in, const int* in_sizes, int n_in,
                              void* d_out, int out_size, void* d_ws,
                              size_t ws_size, hipStream_t stream) {
    const float* x = (const float*)d_in[0];
    const float* amp = (const float*)d_in[1];
    const float* rf = (const float*)d_in[2];
    const float* cf = (const float*)d_in[3];
    const float* rp = (const float*)d_in[4];
    const float* cp = (const float*)d_in[5];
    const float* lA = (const float*)d_in[6];
    const float* lB = (const float*)d_in[7];
    const float* alpha = (const float*)d_in[8];
    const float* beta = (const float*)d_in[9];
    const float* bias = (const float*)d_in[10];
    float* out = (float*)d_out;

    signed char* wq = (signed char*)d_ws;                       // 16 MiB
    signed char* xq = wq + (size_t)OUT_F * IN_F;                // 32 MiB
    float* sw = (float*)(xq + (size_t)N_TOK * IN_F);            // 16 KiB
    float* sx = sw + OUT_F;                                     // 32 KiB

    prep<<<OUT_F / RROWS + N_TOK, 256, 0, stream>>>(
        x, xq, sx, amp, rf, cf, rp, cp, lA, lB, alpha, beta, wq, sw);
    gemm_i8<<<dim3(OUT_F / BN, N_TOK / BM), 256, 0, stream>>>(
        xq, wq, sx, sw, bias, out, N_TOK, OUT_F, IN_F);
}

// Round 5
// 426.787 us; speedup vs baseline: 1.3921x; 1.0076x over previous
//
#include <hip/hip_runtime.h>
#include <hip/hip_bf16.h>
#include <cstdint>

typedef __attribute__((ext_vector_type(4))) float f32x4;
typedef __attribute__((ext_vector_type(4))) int i32x4;

#define IN_F 4096
#define OUT_F 4096
#define N_TOK 8192
#define NUM_FREQ 16
#define RROWS 4  // W rows per block (amortizes per-column cosines 4x)

// ---------- helpers ----------

__device__ inline float fast_tanh(float x) {
    float ax = fabsf(x);
    float e = __expf(2.0f * ax);
    float t = 1.0f - 2.0f / (e + 1.0f);
    return copysignf(t, x);
}

__device__ inline void load_lds16(const void* g, void* l) {
    __builtin_amdgcn_global_load_lds(
        (const __attribute__((address_space(1))) void*)(uintptr_t)g,
        (__attribute__((address_space(3))) void*)(uint32_t)(uintptr_t)l,
        16, 0, 0);
}

__device__ inline int q8(float v, float s) {
    int q = (int)rintf(v * s);
    return min(127, max(-127, q));
}

__device__ inline unsigned int pack4(int q0, int q1, int q2, int q3) {
    return (q0 & 255) | ((q1 & 255) << 8) | ((q2 & 255) << 16) |
           ((q3 & 255) << 24);
}

// ---------- kernel 1: fused W synthesis->i8 + x quantize->i8 ----------
// (unchanged from round 3 — verified passing)
__global__ __launch_bounds__(256)
void prep(const float* __restrict__ x, signed char* __restrict__ xq,
          float* __restrict__ sx, const float* __restrict__ amp,
          const float* __restrict__ rf, const float* __restrict__ cf,
          const float* __restrict__ rp, const float* __restrict__ cp,
          const float* __restrict__ lA, const float* __restrict__ lB,
          const float* __restrict__ alpha, const float* __restrict__ beta,
          signed char* __restrict__ wq, float* __restrict__ sw) {
    const int tid = threadIdx.x;
    const int wave = tid >> 6;
    const int lane = tid & 63;
    __shared__ float s_s[RROWS][NUM_FREQ];
    __shared__ float red[RROWS][4];

    if (blockIdx.x < OUT_F / RROWS) {
        const int o0 = blockIdx.x * RROWS;
        const float step = 6.28318530717958647692f / 4095.0f;
        if (tid < RROWS * NUM_FREQ) {
            const int r = tid >> 4;
            const int k = tid & 15;
            s_s[r][k] =
                amp[k] * __sinf(step * (float)(o0 + r) * rf[k] + rp[k]);
        }
        __syncthreads();

        const int g = lane >> 2;   // element sub-index within 16-group
        const int q = lane & 3;    // freq quad owned by this lane

        float cfr[4], cpr[4];
#pragma unroll
        for (int e = 0; e < 4; ++e) {
            cfr[e] = cf[q * 4 + e];
            cpr[e] = cp[q * 4 + e];
        }
        float skr[RROWS][4];
#pragma unroll
        for (int r = 0; r < RROWS; ++r)
#pragma unroll
            for (int e = 0; e < 4; ++e) skr[r][e] = s_s[r][q * 4 + e];

        const float sa = 1.0f / (1.0f + __expf(-alpha[0]));
        const float sb = 1.0f / (1.0f + __expf(-beta[0]));
        const float stdv = 0.015625f;  // sqrt(2/8192) = 1/64 exactly
        float a0r[RROWS], a1r[RROWS];
#pragma unroll
        for (int r = 0; r < RROWS; ++r) {
            a0r[r] = lA[(o0 + r) * 2 + 0];
            a1r[r] = lA[(o0 + r) * 2 + 1];
        }

        const int ibw = wave * 1024;
        float w[RROWS][16];

#pragma unroll
        for (int j = 0; j < 16; ++j) {
#pragma unroll
            for (int sq = 0; sq < 4; ++sq) {
                const int i = ibw + (j * 4 + sq) * 16 + g;
                const float ci = step * (float)i;
                float cv[4];
#pragma unroll
                for (int e = 0; e < 4; ++e)
                    cv[e] = __cosf(ci * cfr[e] + cpr[e]);
#pragma unroll
                for (int r = 0; r < RROWS; ++r) {
                    float p = skr[r][0] * cv[0] + skr[r][1] * cv[1] +
                              skr[r][2] * cv[2] + skr[r][3] * cv[3];
                    p += __shfl_xor(p, 1);
                    p += __shfl_xor(p, 2);
                    if (q == sq) w[r][j] = p;
                }
            }
        }

#pragma unroll
        for (int j = 0; j < 16; ++j) {
            const int i = ibw + (j * 4 + q) * 16 + g;
            const float b0 = lB[i];
            const float b1 = lB[IN_F + i];
#pragma unroll
            for (int r = 0; r < RROWS; ++r) {
                const float wl = a0r[r] * b0 + a1r[r] * b1;
                w[r][j] = sa * stdv * fast_tanh(w[r][j]) +
                          sb * stdv * fast_tanh(wl);
            }
        }

        float m[RROWS];
#pragma unroll
        for (int r = 0; r < RROWS; ++r) {
            float mm = 0.0f;
#pragma unroll
            for (int j = 0; j < 16; ++j) mm = fmaxf(mm, fabsf(w[r][j]));
#pragma unroll
            for (int off = 32; off > 0; off >>= 1)
                mm = fmaxf(mm, __shfl_xor(mm, off));
            m[r] = mm;
        }
        if (lane == 0) {
#pragma unroll
            for (int r = 0; r < RROWS; ++r) red[r][wave] = m[r];
        }
        __syncthreads();
#pragma unroll
        for (int r = 0; r < RROWS; ++r) {
            float mm = fmaxf(fmaxf(red[r][0], red[r][1]),
                             fmaxf(red[r][2], red[r][3]));
            m[r] = fmaxf(mm, 1e-20f);
        }

#pragma unroll
        for (int r = 0; r < RROWS; ++r) {
            const float s = 127.0f / m[r];
            signed char* wrow = wq + (size_t)(o0 + r) * IN_F;
#pragma unroll
            for (int j = 0; j < 16; ++j) {
                const int i = ibw + (j * 4 + q) * 16 + g;
                wrow[i] = (signed char)q8(w[r][j], s);
            }
        }
        if (tid == 0) {
#pragma unroll
            for (int r = 0; r < RROWS; ++r) sw[o0 + r] = m[r] / 127.0f;
        }
    } else {
        const int t = blockIdx.x - OUT_F / RROWS;
        const f32x4* xr = (const f32x4*)(x + (size_t)t * IN_F);
        f32x4 v[4];
#pragma unroll
        for (int j = 0; j < 4; ++j) v[j] = xr[tid + 256 * j];
        float m = 0.0f;
#pragma unroll
        for (int j = 0; j < 4; ++j)
#pragma unroll
            for (int e = 0; e < 4; ++e) m = fmaxf(m, fabsf(v[j][e]));
#pragma unroll
        for (int off = 32; off > 0; off >>= 1)
            m = fmaxf(m, __shfl_xor(m, off));
        if (lane == 0) red[0][wave] = m;
        __syncthreads();
        m = fmaxf(fmaxf(red[0][0], red[0][1]), fmaxf(red[0][2], red[0][3]));
        m = fmaxf(m, 1e-20f);
        const float s = 127.0f / m;
        unsigned int* orow = (unsigned int*)(xq + (size_t)t * IN_F);
#pragma unroll
        for (int j = 0; j < 4; ++j)
            orow[tid + 256 * j] =
                pack4(q8(v[j][0], s), q8(v[j][1], s), q8(v[j][2], s),
                      q8(v[j][3], s));
        if (tid == 0) sx[t] = m / 127.0f;
    }
}

// ---------- kernel 2: i8 MFMA GEMM, 8-wave counted-vmcnt pipeline ----------
// Round-5 = round-4 resubmission (container failed twice; audit found no
// deadlock path: uniform barrier counts, vmcnt ledger re-derived OK, all
// addresses in-bounds, 128KiB LDS + 512thr = the guide's verified template
// footprint). Hardening added: sched_barrier(0) after EACH s_barrier so no
// LDS read/STAGE can be compiler-hoisted across a barrier (rule #18 class).
//
// Structure (T3+T4+T5): BM=BN=256, 8 waves (2M x 4N), wave tile 128x64.
// LDS ring of 4 half-tile slots (2 dbuf x 2 halves of 128B K-tile),
// staged 3 half-phases ahead via global_load_lds; counted vmcnt(12)
// steady-state (= 3 in-flight half-stages x 4 loads/wave), never 0
// mid-loop. Tails: h0 -> 4 @ t=NT-1; h1 -> 8 @ t=NT-2, 0 @ t=NT-1.
// Per half-phase: vmcnt(N); barrier; 12x ds_read_b128; lgkmcnt(0)+SB;
// barrier; re-stage slot for tile t+2; setprio(1); 32 MFMA; setprio(0).
// Swizzle: identical verified zero-conflict 64B-stride XOR scheme.
#define BM 256
#define BN 256
#define BKB 128
#define SUBK 64

__global__ __launch_bounds__(512, 2)
void gemm_i8(const signed char* __restrict__ A, const signed char* __restrict__ B,
             const float* __restrict__ sx, const float* __restrict__ sw,
             const float* __restrict__ bias, float* __restrict__ C,
             int M, int N, int K) {
    // slot s in [0,4): A at lds[s<<14], B at lds[65536 + (s<<14)]
    __shared__ signed char lds[131072];

    const int tid = threadIdx.x;
    const int wave = tid >> 6;
    const int lane = tid & 63;

    const int bm = blockIdx.y * BM;
    const int bn = blockIdx.x * BN;

    // staging: one call = 16 rows x 64B (1KB, linear in LDS dest).
    // lane l -> row l>>2, source 16B-unit = (l&3) ^ ((l>>3)&3)  [swizzle]
    const int srow = lane >> 2;
    const int scol = (((lane & 3) ^ ((lane >> 3) & 3)) << 4);

    const signed char* gA = A + (size_t)(bm + wave * 16 + srow) * K + scol;
    const signed char* gB = B + (size_t)(bn + wave * 16 + srow) * K + scol;
    const size_t rowK = (size_t)128 * K;  // second 128-row chunk

    // reads: row = wtile + i*16 + lm; 16B unit = quad ^ ((lm>>1)&3)
    const int lm = lane & 15;
    const int quad = lane >> 4;
    const int kq = ((quad ^ ((lm >> 1) & 3)) << 4);

    const int wm = (wave & 1) * 128;   // wave M offset in tile
    const int wn = (wave >> 1) * 64;   // wave N offset in tile (4 waves x 64)
    const int aoff = (wm + lm) * SUBK + kq;
    const int boff = (wn + lm) * SUBK + kq;

    const int NT = K >> 7;  // K-tiles of 128B

    // stage half of a K-tile into ring slot: 4 loads/wave (2 A + 2 B)
    auto STAGE = [&](int slot, int kk) {
        signed char* la = &lds[(slot << 14) + wave * 1024];
        signed char* lb = &lds[65536 + (slot << 14) + wave * 1024];
        load_lds16(gA + kk, la);
        load_lds16(gA + rowK + kk, la + 8192);
        load_lds16(gB + kk, lb);
        load_lds16(gB + rowK + kk, lb + 8192);
    };

    i32x4 acc[8][4] = {};

    // prologue: fill all 4 ring slots (tiles 0 and 1)
    STAGE(0, 0);
    STAGE(1, SUBK);
    STAGE(2, BKB);
    STAGE(3, BKB + SUBK);

    for (int t = 0; t < NT; ++t) {
#pragma unroll
        for (int h = 0; h < 2; ++h) {
            const int slot = ((t & 1) << 1) | h;
            // counted wait: slot's 4 loads retired when outstanding <= N.
            // N = 4 x (#half-stages issued after this slot's).
            if (h == 0) {
                if (t < NT - 1)
                    asm volatile("s_waitcnt vmcnt(12)" ::: "memory");
                else
                    asm volatile("s_waitcnt vmcnt(4)" ::: "memory");
            } else {
                if (t < NT - 2)
                    asm volatile("s_waitcnt vmcnt(12)" ::: "memory");
                else if (t == NT - 2)
                    asm volatile("s_waitcnt vmcnt(8)" ::: "memory");
                else
                    asm volatile("s_waitcnt vmcnt(0)" ::: "memory");
            }
            __builtin_amdgcn_s_barrier();  // all waves' slot-loads landed
            __builtin_amdgcn_sched_barrier(0);  // no read hoists above

            const signed char* pa = &lds[(slot << 14)];
            const signed char* pb = &lds[65536 + (slot << 14)];
            i32x4 af[8], bv[4];
#pragma unroll
            for (int i = 0; i < 8; ++i)
                af[i] = *(const i32x4*)(pa + aoff + i * 1024);
#pragma unroll
            for (int i = 0; i < 4; ++i)
                bv[i] = *(const i32x4*)(pb + boff + i * 1024);
            asm volatile("s_waitcnt lgkmcnt(0)" ::: "memory");
            __builtin_amdgcn_sched_barrier(0);  // rule #18: pin MFMA after
            __builtin_amdgcn_s_barrier();  // all waves done reading slot
            __builtin_amdgcn_sched_barrier(0);  // no STAGE hoists above

            if (t + 2 < NT) STAGE(slot, (t + 2) * BKB + h * SUBK);
            __builtin_amdgcn_sched_barrier(0);

            __builtin_amdgcn_s_setprio(1);
#pragma unroll
            for (int im = 0; im < 8; ++im)
#pragma unroll
                for (int in = 0; in < 4; ++in)
                    acc[im][in] = __builtin_amdgcn_mfma_i32_16x16x64_i8(
                        af[im], bv[in], acc[im][in], 0, 0, 0);
            __builtin_amdgcn_s_setprio(0);
        }
    }

    // epilogue: D layout col = lane&15, row = quad*4 + r
    float sxv[8][4];
#pragma unroll
    for (int im = 0; im < 8; ++im)
#pragma unroll
        for (int r = 0; r < 4; ++r)
            sxv[im][r] = sx[bm + wm + im * 16 + quad * 4 + r];

#pragma unroll
    for (int in = 0; in < 4; ++in) {
        const int cn = bn + wn + in * 16 + lm;
        const float bv_ = bias[cn];
        const float scw = sw[cn];
#pragma unroll
        for (int im = 0; im < 8; ++im) {
            const int rm = bm + wm + im * 16 + quad * 4;
#pragma unroll
            for (int r = 0; r < 4; ++r)
                C[(size_t)(rm + r) * N + cn] =
                    (float)acc[im][in][r] * (sxv[im][r] * scw) + bv_;
        }
    }
}

// ---------- launch ----------
extern "C" void kernel_launch(void* const* d_in, const int* in_sizes, int n_in,
                              void* d_out, int out_size, void* d_ws,
                              size_t ws_size, hipStream_t stream) {
    const float* x = (const float*)d_in[0];
    const float* amp = (const float*)d_in[1];
    const float* rf = (const float*)d_in[2];
    const float* cf = (const float*)d_in[3];
    const float* rp = (const float*)d_in[4];
    const float* cp = (const float*)d_in[5];
    const float* lA = (const float*)d_in[6];
    const float* lB = (const float*)d_in[7];
    const float* alpha = (const float*)d_in[8];
    const float* beta = (const float*)d_in[9];
    const float* bias = (const float*)d_in[10];
    float* out = (float*)d_out;

    signed char* wq = (signed char*)d_ws;                       // 16 MiB
    signed char* xq = wq + (size_t)OUT_F * IN_F;                // 32 MiB
    float* sw = (float*)(xq + (size_t)N_TOK * IN_F);            // 16 KiB
    float* sx = sw + OUT_F;                                     // 32 KiB

    prep<<<OUT_F / RROWS + N_TOK, 256, 0, stream>>>(
        x, xq, sx, amp, rf, cf, rp, cp, lA, lB, alpha, beta, wq, sw);
    gemm_i8<<<dim3(OUT_F / BN, N_TOK / BM), 512, 0, stream>>>(
        xq, wq, sx, sw, bias, out, N_TOK, OUT_F, IN_F);
}